// Round 1
// baseline (335.975 us; speedup 1.0000x reference)
//
#include <hip/hip_runtime.h>

// Problem constants (CausalAttention: B=4, S=2048, D_IN=D_OUT=1024, single head)
#define Bb 4
#define Ss 2048
#define Dd 1024

typedef unsigned short u16;
typedef __bf16 bf16x8 __attribute__((ext_vector_type(8)));
typedef float  f32x4  __attribute__((ext_vector_type(4)));

__device__ inline u16 f2bf(float f) {
  union { float f; unsigned u; } x; x.f = f;
  unsigned u = x.u;
  return (u16)((u + 0x7fffu + ((u >> 16) & 1u)) >> 16);  // RNE
}
__device__ inline float bf2f(u16 h) {
  union { unsigned u; float f; } x; x.u = ((unsigned)h) << 16;
  return x.f;
}

// ---------------- cast fp32 -> bf16 ----------------
__global__ __launch_bounds__(256) void cast_kernel(const float* __restrict__ in,
                                                   u16* __restrict__ out, int n) {
  int i = (blockIdx.x * 256 + threadIdx.x) * 4;
  if (i >= n) return;
  float4 v = *(const float4*)(in + i);
  unsigned p0 = (unsigned)f2bf(v.x) | ((unsigned)f2bf(v.y) << 16);
  unsigned p1 = (unsigned)f2bf(v.z) | ((unsigned)f2bf(v.w) << 16);
  uint2 p; p.x = p0; p.y = p1;
  *(uint2*)(out + i) = p;
}

// ---------------- shared GEMM core (C = A * B^T), bf16 in, fp32 acc ----------------
// A: [*, lda] row-major (K contiguous), tile rows = BM
// B: [*, ldb] row-major (K contiguous), tile rows = BN (i.e. B is stored [N,K])
#define BM 128
#define BN 128
#define BK 32
#define LSTR 40  // 32 + 8 pad (u16 units) -> 80B row stride, 16B aligned

__device__ inline void gemm_tile(const u16* __restrict__ A, int lda,
                                 const u16* __restrict__ Bp, int ldb,
                                 int kBeg, int kEnd,
                                 u16* lA, u16* lB, f32x4 acc[4][4]) {
  const int tid  = threadIdx.x;
  const int lane = tid & 63, wave = tid >> 6;
  const int quad = lane >> 4, r16 = lane & 15;
  const int wm = (wave & 1) * 64, wn = (wave >> 1) * 64;

  for (int k0 = kBeg; k0 < kEnd; k0 += BK) {
    __syncthreads();
    // stage A tile: 128 rows x 32 cols bf16 (64B/row = 4 x 16B segs)
#pragma unroll
    for (int s = tid; s < 512; s += 256) {
      int row = s >> 2, part = s & 3;
      *(uint4*)(lA + row * LSTR + part * 8) =
          *(const uint4*)(A + (size_t)row * lda + k0 + part * 8);
    }
#pragma unroll
    for (int s = tid; s < 512; s += 256) {
      int row = s >> 2, part = s & 3;
      *(uint4*)(lB + row * LSTR + part * 8) =
          *(const uint4*)(Bp + (size_t)row * ldb + k0 + part * 8);
    }
    __syncthreads();
    // fragments: A[m=lane&15][k=quad*8+j] -> contiguous 8 bf16 from LDS row
    bf16x8 fa[4], fb[4];
#pragma unroll
    for (int t = 0; t < 4; t++)
      fa[t] = *(const bf16x8*)(lA + (wm + t * 16 + r16) * LSTR + quad * 8);
#pragma unroll
    for (int t = 0; t < 4; t++)
      fb[t] = *(const bf16x8*)(lB + (wn + t * 16 + r16) * LSTR + quad * 8);
#pragma unroll
    for (int tm = 0; tm < 4; tm++)
#pragma unroll
      for (int tn = 0; tn < 4; tn++)
        acc[tm][tn] = __builtin_amdgcn_mfma_f32_16x16x32_bf16(fa[tm], fb[tn],
                                                              acc[tm][tn], 0, 0, 0);
  }
}

// ---------------- QKV projection: [8192,1024] x [1024,1024]^T, z selects W ----------------
__global__ __launch_bounds__(256) void qkv_gemm(const u16* __restrict__ xb,
                                                const u16* __restrict__ wb,
                                                u16* __restrict__ qkv) {
  __shared__ __align__(16) u16 lA[BM * LSTR];
  __shared__ __align__(16) u16 lB[BN * LSTR];
  const int zi = blockIdx.z;
  const int row0 = blockIdx.y * BM;  // M = B*S = 8192
  const int col0 = blockIdx.x * BN;  // N = 1024
  const u16* A  = xb + (size_t)row0 * Dd;
  const u16* Bp = wb + (size_t)zi * Dd * Dd + (size_t)col0 * Dd;
  f32x4 acc[4][4];
  const f32x4 zero = {0.f, 0.f, 0.f, 0.f};
#pragma unroll
  for (int tm = 0; tm < 4; tm++)
#pragma unroll
    for (int tn = 0; tn < 4; tn++) acc[tm][tn] = zero;

  gemm_tile(A, Dd, Bp, Dd, 0, Dd, lA, lB, acc);

  u16* out = qkv + (size_t)zi * ((size_t)Bb * Ss * Dd);
  const int lane = threadIdx.x & 63, wave = threadIdx.x >> 6;
  const int quad = lane >> 4, r16 = lane & 15;
  const int wm = (wave & 1) * 64, wn = (wave >> 1) * 64;
#pragma unroll
  for (int tm = 0; tm < 4; tm++)
#pragma unroll
    for (int tn = 0; tn < 4; tn++) {
      int rr = row0 + wm + tm * 16 + quad * 4;
      int cc = col0 + wn + tn * 16 + r16;
#pragma unroll
      for (int r = 0; r < 4; r++)
        out[(size_t)(rr + r) * Dd + cc] = f2bf(acc[tm][tn][r]);
    }
}

// ---------------- scores: S = (Q K^T) * 1/32, lower-triangular tiles only ----------------
__global__ __launch_bounds__(256) void scores_gemm(const u16* __restrict__ qb,
                                                   const u16* __restrict__ kb,
                                                   u16* __restrict__ sc) {
  const int jt = blockIdx.x, it = blockIdx.y, b = blockIdx.z;
  if (jt > it) return;  // fully-masked tile: never stored, softmax never reads it
  __shared__ __align__(16) u16 lA[BM * LSTR];
  __shared__ __align__(16) u16 lB[BN * LSTR];
  const u16* A  = qb + (size_t)b * Ss * Dd + (size_t)it * BM * Dd;
  const u16* Bp = kb + (size_t)b * Ss * Dd + (size_t)jt * BN * Dd;
  f32x4 acc[4][4];
  const f32x4 zero = {0.f, 0.f, 0.f, 0.f};
#pragma unroll
  for (int tm = 0; tm < 4; tm++)
#pragma unroll
    for (int tn = 0; tn < 4; tn++) acc[tm][tn] = zero;

  gemm_tile(A, Dd, Bp, Dd, 0, Dd, lA, lB, acc);

  u16* out = sc + (size_t)b * Ss * Ss;
  const int lane = threadIdx.x & 63, wave = threadIdx.x >> 6;
  const int quad = lane >> 4, r16 = lane & 15;
  const int wm = (wave & 1) * 64, wn = (wave >> 1) * 64;
#pragma unroll
  for (int tm = 0; tm < 4; tm++)
#pragma unroll
    for (int tn = 0; tn < 4; tn++) {
      int rr = it * BM + wm + tm * 16 + quad * 4;
      int cc = jt * BN + wn + tn * 16 + r16;
#pragma unroll
      for (int r = 0; r < 4; r++)
        out[(size_t)(rr + r) * Ss + cc] = f2bf(acc[tm][tn][r] * 0.03125f);
    }
}

// ---------------- row softmax in place (bf16), zero-fill above diagonal ----------------
__global__ __launch_bounds__(256) void softmax_kernel(u16* __restrict__ sc) {
  const int bid = blockIdx.x;       // 0..B*S-1
  const int b = bid >> 11;          // / 2048
  const int i = bid & 2047;
  u16* row = sc + (size_t)b * Ss * Ss + (size_t)i * Ss;
  const int n = i + 1;
  __shared__ float buf[Ss];
  __shared__ float red[4];
  const int tid = threadIdx.x, lane = tid & 63, wave = tid >> 6;

  float m = -3.4e38f;
  for (int j = tid; j < n; j += 256) {
    float v = bf2f(row[j]);
    buf[j] = v;
    m = fmaxf(m, v);
  }
  for (int o = 32; o; o >>= 1) m = fmaxf(m, __shfl_xor(m, o));
  if (lane == 0) red[wave] = m;
  __syncthreads();
  m = fmaxf(fmaxf(red[0], red[1]), fmaxf(red[2], red[3]));
  __syncthreads();  // red reused below

  float l = 0.f;
  for (int j = tid; j < n; j += 256) {
    float e = __expf(buf[j] - m);
    buf[j] = e;
    l += e;
  }
  for (int o = 32; o; o >>= 1) l += __shfl_xor(l, o);
  if (lane == 0) red[wave] = l;
  __syncthreads();
  l = red[0] + red[1] + red[2] + red[3];
  float inv = 1.f / l;
  for (int j = tid; j < Ss; j += 256)
    row[j] = (j < n) ? f2bf(buf[j] * inv) : (u16)0;
}

// ---------------- V transpose: vt[b,e,s] = vb[b,s,e] (so PV is same NT GEMM) ----------------
__global__ __launch_bounds__(256) void transpose_v(const u16* __restrict__ vb,
                                                   u16* __restrict__ vt) {
  const int b = blockIdx.z;
  const int s0 = blockIdx.x * 64;
  const int e0 = blockIdx.y * 64;
  __shared__ __align__(16) u16 t[64][72];  // 144B row stride, 16B aligned
  const int tid = threadIdx.x;
  const u16* src = vb + (size_t)b * Ss * Dd;
#pragma unroll
  for (int g = tid; g < 512; g += 256) {
    int row = g >> 3, part = g & 7;
    uint4 v = *(const uint4*)(src + (size_t)(s0 + row) * Dd + e0 + part * 8);
    const u16* pv = (const u16*)&v;
#pragma unroll
    for (int j = 0; j < 8; j++) t[part * 8 + j][row] = pv[j];
  }
  __syncthreads();
  u16* dst = vt + (size_t)b * Dd * Ss;
#pragma unroll
  for (int g = tid; g < 512; g += 256) {
    int e = g >> 3, part = g & 7;
    uint4 v = *(const uint4*)(&t[e][part * 8]);
    *(uint4*)(dst + (size_t)(e0 + e) * Ss + s0 + part * 8) = v;
  }
}

// ---------------- PV: O = P * V  (P:[2048,2048] bf16, Vt:[1024,2048] bf16) ----------------
__global__ __launch_bounds__(256) void pv_gemm(const u16* __restrict__ sc,
                                               const u16* __restrict__ vt,
                                               float* __restrict__ out) {
  const int b = blockIdx.z;
  const int row0 = blockIdx.y * BM;  // M = 2048
  const int col0 = blockIdx.x * BN;  // N = 1024
  __shared__ __align__(16) u16 lA[BM * LSTR];
  __shared__ __align__(16) u16 lB[BN * LSTR];
  const u16* A  = sc + (size_t)b * Ss * Ss + (size_t)row0 * Ss;
  const u16* Bp = vt + (size_t)b * Dd * Ss + (size_t)col0 * Ss;
  f32x4 acc[4][4];
  const f32x4 zero = {0.f, 0.f, 0.f, 0.f};
#pragma unroll
  for (int tm = 0; tm < 4; tm++)
#pragma unroll
    for (int tn = 0; tn < 4; tn++) acc[tm][tn] = zero;

  // causal: P[q,k]==0 for k > q, so K-loop only needs k < row0+BM
  gemm_tile(A, Ss, Bp, Ss, 0, row0 + BM, lA, lB, acc);

  float* o = out + (size_t)b * Ss * Dd;
  const int lane = threadIdx.x & 63, wave = threadIdx.x >> 6;
  const int quad = lane >> 4, r16 = lane & 15;
  const int wm = (wave & 1) * 64, wn = (wave >> 1) * 64;
#pragma unroll
  for (int tm = 0; tm < 4; tm++)
#pragma unroll
    for (int tn = 0; tn < 4; tn++) {
      int rr = row0 + wm + tm * 16 + quad * 4;
      int cc = col0 + wn + tn * 16 + r16;
#pragma unroll
      for (int r = 0; r < 4; r++)
        o[(size_t)(rr + r) * Dd + cc] = acc[tm][tn][r];
    }
}

// ---------------- launch ----------------
// Workspace layout (bytes), total 106,954,752 (~102 MB):
//   qkv : [0, 50331648)           q,k,v bf16, each 16 MB
//   sc  : [50331648, 83886080)    scores/P bf16, 32 MB
//   xb  : [83886080, 100663296)   x bf16 16 MB; REUSED as vt after qkv_gemm
//   wb  : [100663296, 106954752)  wq|wk|wv bf16, 6 MB
extern "C" void kernel_launch(void* const* d_in, const int* in_sizes, int n_in,
                              void* d_out, int out_size, void* d_ws, size_t ws_size,
                              hipStream_t stream) {
  const float* x  = (const float*)d_in[0];
  const float* wq = (const float*)d_in[1];
  const float* wk = (const float*)d_in[2];
  const float* wv = (const float*)d_in[3];
  float* out = (float*)d_out;
  char* ws = (char*)d_ws;
  if (ws_size < 106954752u) return;  // clean fail rather than OOB corruption

  u16* qkv = (u16*)(ws);
  u16* sc  = (u16*)(ws + 50331648u);
  u16* xb  = (u16*)(ws + 83886080u);
  u16* vt  = xb;  // alias: x dead after qkv_gemm
  u16* wb  = (u16*)(ws + 100663296u);

  const size_t nQ = (size_t)Bb * Ss * Dd;  // 8388608

  cast_kernel<<<8192, 256, 0, stream>>>(x, xb, (int)nQ);
  cast_kernel<<<1024, 256, 0, stream>>>(wq, wb, Dd * Dd);
  cast_kernel<<<1024, 256, 0, stream>>>(wk, wb + (size_t)Dd * Dd, Dd * Dd);
  cast_kernel<<<1024, 256, 0, stream>>>(wv, wb + 2 * (size_t)Dd * Dd, Dd * Dd);

  qkv_gemm<<<dim3(Dd / BN, (Bb * Ss) / BM, 3), 256, 0, stream>>>(xb, wb, qkv);
  scores_gemm<<<dim3(Ss / BN, Ss / BM, Bb), 256, 0, stream>>>(qkv, qkv + nQ, sc);
  softmax_kernel<<<Bb * Ss, 256, 0, stream>>>(sc);
  transpose_v<<<dim3(Ss / 64, Dd / 64, Bb), 256, 0, stream>>>(qkv + 2 * nQ, vt);
  pv_gemm<<<dim3(Dd / BN, Ss / BM, Bb), 256, 0, stream>>>(sc, vt, out);
}

// Round 2
// 289.623 us; speedup vs baseline: 1.1600x; 1.1600x over previous
//
#include <hip/hip_runtime.h>

// Problem constants (CausalAttention: B=4, S=2048, D_IN=D_OUT=1024, single head)
#define Bb 4
#define Ss 2048
#define Dd 1024

typedef unsigned short u16;
typedef __bf16 bf16x8 __attribute__((ext_vector_type(8)));
typedef float  f32x4  __attribute__((ext_vector_type(4)));

__device__ inline u16 f2bf(float f) {
  union { float f; unsigned u; } x; x.f = f;
  unsigned u = x.u;
  return (u16)((u + 0x7fffu + ((u >> 16) & 1u)) >> 16);  // RNE
}
__device__ inline float bf2f(u16 h) {
  union { unsigned u; float f; } x; x.u = ((unsigned)h) << 16;
  return x.f;
}

// async global->LDS, 16B per lane. LDS dest is wave-uniform base + lane*16:
// lane order must match LDS contiguity (C-style cast is the only addrspace
// cast clang accepts here).
__device__ static inline void gl_lds16(const u16* g, u16* l) {
  __builtin_amdgcn_global_load_lds((__attribute__((address_space(1))) const void*)g,
                                   (__attribute__((address_space(3))) void*)l,
                                   16, 0, 0);
}

// ---------------- cast fp32 -> bf16 ----------------
__global__ __launch_bounds__(256) void cast_kernel(const float* __restrict__ in,
                                                   u16* __restrict__ out, int n) {
  int i = (blockIdx.x * 256 + threadIdx.x) * 4;
  if (i >= n) return;
  float4 v = *(const float4*)(in + i);
  unsigned p0 = (unsigned)f2bf(v.x) | ((unsigned)f2bf(v.y) << 16);
  unsigned p1 = (unsigned)f2bf(v.z) | ((unsigned)f2bf(v.w) << 16);
  uint2 p; p.x = p0; p.y = p1;
  *(uint2*)(out + i) = p;
}

// weights: 3 sources, blockIdx.y selects
__global__ __launch_bounds__(256) void cast3_kernel(const float* __restrict__ w0,
                                                    const float* __restrict__ w1,
                                                    const float* __restrict__ w2,
                                                    u16* __restrict__ out) {
  const float* src = (blockIdx.y == 0) ? w0 : (blockIdx.y == 1) ? w1 : w2;
  u16* dst = out + (size_t)blockIdx.y * Dd * Dd;
  int i = (blockIdx.x * 256 + threadIdx.x) * 4;
  float4 v = *(const float4*)(src + i);
  unsigned p0 = (unsigned)f2bf(v.x) | ((unsigned)f2bf(v.y) << 16);
  unsigned p1 = (unsigned)f2bf(v.z) | ((unsigned)f2bf(v.w) << 16);
  uint2 p; p.x = p0; p.y = p1;
  *(uint2*)(dst + i) = p;
}

// ---------------- shared GEMM core (C = A * B^T), bf16 in, fp32 acc ----------------
// A: [*, lda] row-major (K contiguous), tile rows = BM
// B: [*, ldb] row-major (K contiguous), tile rows = BN (i.e. B stored [N,K])
// LDS: unpadded, row stride 32 u16 (64B); segment s=(row*4+part) at byte s*16.
#define BM 128
#define BN 128
#define BK 32

__device__ inline void gemm_tile(const u16* __restrict__ A, int lda,
                                 const u16* __restrict__ Bp, int ldb,
                                 int kBeg, int kEnd,
                                 u16* lA, u16* lB, f32x4 acc[4][4]) {
  const int tid  = threadIdx.x;
  const int lane = tid & 63, wave = tid >> 6;
  const int quad = lane >> 4, r16 = lane & 15;
  const int wm = (wave & 1) * 64, wn = (wave >> 1) * 64;

  for (int k0 = kBeg; k0 < kEnd; k0 += BK) {
    __syncthreads();  // previous iter's ds_reads done before overwrite
#pragma unroll
    for (int q = 0; q < 2; q++) {
      int s = q * 256 + tid;          // segment 0..511; within-wave: lane-contig
      int row = s >> 2, part = s & 3;
      gl_lds16(A + (size_t)row * lda + k0 + part * 8, lA + s * 8);
    }
#pragma unroll
    for (int q = 0; q < 2; q++) {
      int s = q * 256 + tid;
      int row = s >> 2, part = s & 3;
      gl_lds16(Bp + (size_t)row * ldb + k0 + part * 8, lB + s * 8);
    }
    __syncthreads();  // emits s_waitcnt vmcnt(0) + s_barrier (drains DMA)
    bf16x8 fa[4], fb[4];
#pragma unroll
    for (int t = 0; t < 4; t++)
      fa[t] = *(const bf16x8*)(lA + (wm + t * 16 + r16) * 32 + quad * 8);
#pragma unroll
    for (int t = 0; t < 4; t++)
      fb[t] = *(const bf16x8*)(lB + (wn + t * 16 + r16) * 32 + quad * 8);
#pragma unroll
    for (int tm = 0; tm < 4; tm++)
#pragma unroll
      for (int tn = 0; tn < 4; tn++)
        acc[tm][tn] = __builtin_amdgcn_mfma_f32_16x16x32_bf16(fa[tm], fb[tn],
                                                              acc[tm][tn], 0, 0, 0);
  }
}

// ---------------- QKV projection: [8192,1024] x [1024,1024]^T, z selects W ----------------
__global__ __launch_bounds__(256) void qkv_gemm(const u16* __restrict__ xb,
                                                const u16* __restrict__ wb,
                                                u16* __restrict__ qkv) {
  __shared__ __align__(16) u16 lA[BM * 32];
  __shared__ __align__(16) u16 lB[BN * 32];
  const int zi = blockIdx.z;
  const int row0 = blockIdx.y * BM;  // M = B*S = 8192
  const int col0 = blockIdx.x * BN;  // N = 1024
  const u16* A  = xb + (size_t)row0 * Dd;
  const u16* Bp = wb + (size_t)zi * Dd * Dd + (size_t)col0 * Dd;
  f32x4 acc[4][4];
  const f32x4 zero = {0.f, 0.f, 0.f, 0.f};
#pragma unroll
  for (int tm = 0; tm < 4; tm++)
#pragma unroll
    for (int tn = 0; tn < 4; tn++) acc[tm][tn] = zero;

  gemm_tile(A, Dd, Bp, Dd, 0, Dd, lA, lB, acc);

  u16* out = qkv + (size_t)zi * ((size_t)Bb * Ss * Dd);
  const int lane = threadIdx.x & 63, wave = threadIdx.x >> 6;
  const int quad = lane >> 4, r16 = lane & 15;
  const int wm = (wave & 1) * 64, wn = (wave >> 1) * 64;
#pragma unroll
  for (int tm = 0; tm < 4; tm++)
#pragma unroll
    for (int tn = 0; tn < 4; tn++) {
      int rr = row0 + wm + tm * 16 + quad * 4;
      int cc = col0 + wn + tn * 16 + r16;
#pragma unroll
      for (int r = 0; r < 4; r++)
        out[(size_t)(rr + r) * Dd + cc] = f2bf(acc[tm][tn][r]);
    }
}

// ---------------- scores: S = (Q K^T) * 1/32, lower-triangular tiles only ----------------
__global__ __launch_bounds__(256) void scores_gemm(const u16* __restrict__ qb,
                                                   const u16* __restrict__ kb,
                                                   u16* __restrict__ sc) {
  const int jt = blockIdx.x, it = blockIdx.y, b = blockIdx.z;
  if (jt > it) return;  // fully-masked tile: never stored, softmax never reads it
  __shared__ __align__(16) u16 lA[BM * 32];
  __shared__ __align__(16) u16 lB[BN * 32];
  const u16* A  = qb + (size_t)b * Ss * Dd + (size_t)it * BM * Dd;
  const u16* Bp = kb + (size_t)b * Ss * Dd + (size_t)jt * BN * Dd;
  f32x4 acc[4][4];
  const f32x4 zero = {0.f, 0.f, 0.f, 0.f};
#pragma unroll
  for (int tm = 0; tm < 4; tm++)
#pragma unroll
    for (int tn = 0; tn < 4; tn++) acc[tm][tn] = zero;

  gemm_tile(A, Dd, Bp, Dd, 0, Dd, lA, lB, acc);

  u16* out = sc + (size_t)b * Ss * Ss;
  const int lane = threadIdx.x & 63, wave = threadIdx.x >> 6;
  const int quad = lane >> 4, r16 = lane & 15;
  const int wm = (wave & 1) * 64, wn = (wave >> 1) * 64;
#pragma unroll
  for (int tm = 0; tm < 4; tm++)
#pragma unroll
    for (int tn = 0; tn < 4; tn++) {
      int rr = it * BM + wm + tm * 16 + quad * 4;
      int cc = jt * BN + wn + tn * 16 + r16;
#pragma unroll
      for (int r = 0; r < 4; r++)
        out[(size_t)(rr + r) * Ss + cc] = f2bf(acc[tm][tn][r] * 0.03125f);
    }
}

// ---------------- row softmax in place (bf16), zero-fill above diagonal ----------------
__global__ __launch_bounds__(256) void softmax_kernel(u16* __restrict__ sc) {
  const int bid = blockIdx.x;       // 0..B*S-1
  const int b = bid >> 11;          // / 2048
  const int i = bid & 2047;
  u16* row = sc + (size_t)b * Ss * Ss + (size_t)i * Ss;
  const int n = i + 1;
  __shared__ float buf[Ss];
  __shared__ float red[4];
  const int tid = threadIdx.x, lane = tid & 63, wave = tid >> 6;

  float m = -3.4e38f;
  for (int j = tid; j < n; j += 256) {
    float v = bf2f(row[j]);
    buf[j] = v;
    m = fmaxf(m, v);
  }
  for (int o = 32; o; o >>= 1) m = fmaxf(m, __shfl_xor(m, o));
  if (lane == 0) red[wave] = m;
  __syncthreads();
  m = fmaxf(fmaxf(red[0], red[1]), fmaxf(red[2], red[3]));
  __syncthreads();  // red reused below

  float l = 0.f;
  for (int j = tid; j < n; j += 256) {
    float e = __expf(buf[j] - m);
    buf[j] = e;
    l += e;
  }
  for (int o = 32; o; o >>= 1) l += __shfl_xor(l, o);
  if (lane == 0) red[wave] = l;
  __syncthreads();
  l = red[0] + red[1] + red[2] + red[3];
  float inv = 1.f / l;
  for (int j = tid; j < Ss; j += 256)
    row[j] = (j < n) ? f2bf(buf[j] * inv) : (u16)0;
}

// ---------------- V transpose: vt[b,e,s] = vb[b,s,e] (so PV is same NT GEMM) ----------------
__global__ __launch_bounds__(256) void transpose_v(const u16* __restrict__ vb,
                                                   u16* __restrict__ vt) {
  const int b = blockIdx.z;
  const int s0 = blockIdx.x * 64;
  const int e0 = blockIdx.y * 64;
  __shared__ __align__(16) u16 t[64][72];  // 144B row stride, 16B aligned
  const int tid = threadIdx.x;
  const u16* src = vb + (size_t)b * Ss * Dd;
#pragma unroll
  for (int g = tid; g < 512; g += 256) {
    int row = g >> 3, part = g & 7;
    uint4 v = *(const uint4*)(src + (size_t)(s0 + row) * Dd + e0 + part * 8);
    const u16* pv = (const u16*)&v;
#pragma unroll
    for (int j = 0; j < 8; j++) t[part * 8 + j][row] = pv[j];
  }
  __syncthreads();
  u16* dst = vt + (size_t)b * Dd * Ss;
#pragma unroll
  for (int g = tid; g < 512; g += 256) {
    int e = g >> 3, part = g & 7;
    uint4 v = *(const uint4*)(&t[e][part * 8]);
    *(uint4*)(dst + (size_t)(e0 + e) * Ss + s0 + part * 8) = v;
  }
}

// ---------------- PV: O = P * V  (P:[2048,2048] bf16, Vt:[1024,2048] bf16) ----------------
__global__ __launch_bounds__(256) void pv_gemm(const u16* __restrict__ sc,
                                               const u16* __restrict__ vt,
                                               float* __restrict__ out) {
  const int b = blockIdx.z;
  const int row0 = blockIdx.y * BM;  // M = 2048
  const int col0 = blockIdx.x * BN;  // N = 1024
  __shared__ __align__(16) u16 lA[BM * 32];
  __shared__ __align__(16) u16 lB[BN * 32];
  const u16* A  = sc + (size_t)b * Ss * Ss + (size_t)row0 * Ss;
  const u16* Bp = vt + (size_t)b * Dd * Ss + (size_t)col0 * Ss;
  f32x4 acc[4][4];
  const f32x4 zero = {0.f, 0.f, 0.f, 0.f};
#pragma unroll
  for (int tm = 0; tm < 4; tm++)
#pragma unroll
    for (int tn = 0; tn < 4; tn++) acc[tm][tn] = zero;

  // causal: P[q,k]==0 for k > q, so K-loop only needs k < row0+BM
  gemm_tile(A, Ss, Bp, Ss, 0, row0 + BM, lA, lB, acc);

  float* o = out + (size_t)b * Ss * Dd;
  const int lane = threadIdx.x & 63, wave = threadIdx.x >> 6;
  const int quad = lane >> 4, r16 = lane & 15;
  const int wm = (wave & 1) * 64, wn = (wave >> 1) * 64;
#pragma unroll
  for (int tm = 0; tm < 4; tm++)
#pragma unroll
    for (int tn = 0; tn < 4; tn++) {
      int rr = row0 + wm + tm * 16 + quad * 4;
      int cc = col0 + wn + tn * 16 + r16;
#pragma unroll
      for (int r = 0; r < 4; r++)
        o[(size_t)(rr + r) * Dd + cc] = acc[tm][tn][r];
    }
}

// ---------------- launch ----------------
// Workspace layout (bytes), total 106,954,752 (~102 MB):
//   qkv : [0, 50331648)           q,k,v bf16, each 16 MB
//   sc  : [50331648, 83886080)    scores/P bf16, 32 MB
//   xb  : [83886080, 100663296)   x bf16 16 MB; REUSED as vt after qkv_gemm
//   wb  : [100663296, 106954752)  wq|wk|wv bf16, 6 MB
extern "C" void kernel_launch(void* const* d_in, const int* in_sizes, int n_in,
                              void* d_out, int out_size, void* d_ws, size_t ws_size,
                              hipStream_t stream) {
  const float* x  = (const float*)d_in[0];
  const float* wq = (const float*)d_in[1];
  const float* wk = (const float*)d_in[2];
  const float* wv = (const float*)d_in[3];
  float* out = (float*)d_out;
  char* ws = (char*)d_ws;
  if (ws_size < 106954752u) return;  // clean fail rather than OOB corruption

  u16* qkv = (u16*)(ws);
  u16* sc  = (u16*)(ws + 50331648u);
  u16* xb  = (u16*)(ws + 83886080u);
  u16* vt  = xb;  // alias: x dead after qkv_gemm
  u16* wb  = (u16*)(ws + 100663296u);

  const size_t nQ = (size_t)Bb * Ss * Dd;  // 8388608

  cast_kernel<<<8192, 256, 0, stream>>>(x, xb, (int)nQ);
  cast3_kernel<<<dim3(1024, 3), 256, 0, stream>>>(wq, wk, wv, wb);

  qkv_gemm<<<dim3(Dd / BN, (Bb * Ss) / BM, 3), 256, 0, stream>>>(xb, wb, qkv);
  scores_gemm<<<dim3(Ss / BN, Ss / BM, Bb), 256, 0, stream>>>(qkv, qkv + nQ, sc);
  softmax_kernel<<<Bb * Ss, 256, 0, stream>>>(sc);
  transpose_v<<<dim3(Ss / 64, Dd / 64, Bb), 256, 0, stream>>>(qkv + 2 * nQ, vt);
  pv_gemm<<<dim3(Dd / BN, Ss / BM, Bb), 256, 0, stream>>>(sc, vt, out);
}

// Round 3
// 273.739 us; speedup vs baseline: 1.2274x; 1.0580x over previous
//
#include <hip/hip_runtime.h>

// Problem constants (CausalAttention: B=4, S=2048, D_IN=D_OUT=1024, single head)
#define Bb 4
#define Ss 2048
#define Dd 1024

typedef unsigned short u16;
typedef __bf16 bf16x8 __attribute__((ext_vector_type(8)));
typedef float  f32x4  __attribute__((ext_vector_type(4)));

__device__ inline u16 f2bf(float f) {
  union { float f; unsigned u; } x; x.f = f;
  unsigned u = x.u;
  return (u16)((u + 0x7fffu + ((u >> 16) & 1u)) >> 16);  // RNE
}

// async global->LDS, 16B per lane. LDS dest is wave-uniform base + lane*16:
// lane order must match LDS contiguity.
__device__ static inline void gl_lds16(const u16* g, u16* l) {
  __builtin_amdgcn_global_load_lds((__attribute__((address_space(1))) const void*)g,
                                   (__attribute__((address_space(3))) void*)l,
                                   16, 0, 0);
}

// ---------------- cast fp32 -> bf16 ----------------
__global__ __launch_bounds__(256) void cast_kernel(const float* __restrict__ in,
                                                   u16* __restrict__ out, int n) {
  int i = (blockIdx.x * 256 + threadIdx.x) * 4;
  if (i >= n) return;
  float4 v = *(const float4*)(in + i);
  unsigned p0 = (unsigned)f2bf(v.x) | ((unsigned)f2bf(v.y) << 16);
  unsigned p1 = (unsigned)f2bf(v.z) | ((unsigned)f2bf(v.w) << 16);
  uint2 p; p.x = p0; p.y = p1;
  *(uint2*)(out + i) = p;
}

// weights: 3 sources, blockIdx.y selects
__global__ __launch_bounds__(256) void cast3_kernel(const float* __restrict__ w0,
                                                    const float* __restrict__ w1,
                                                    const float* __restrict__ w2,
                                                    u16* __restrict__ out) {
  const float* src = (blockIdx.y == 0) ? w0 : (blockIdx.y == 1) ? w1 : w2;
  u16* dst = out + (size_t)blockIdx.y * Dd * Dd;
  int i = (blockIdx.x * 256 + threadIdx.x) * 4;
  float4 v = *(const float4*)(src + i);
  unsigned p0 = (unsigned)f2bf(v.x) | ((unsigned)f2bf(v.y) << 16);
  unsigned p1 = (unsigned)f2bf(v.z) | ((unsigned)f2bf(v.w) << 16);
  uint2 p; p.x = p0; p.y = p1;
  *(uint2*)(dst + i) = p;
}

// ---------------- shared GEMM core (C = A * B^T), bf16 in, fp32 acc ----------------
// LDS: unpadded, row stride 32 u16 (64B); segment s=(row*4+part) at byte s*16.
#define BM 128
#define BN 128
#define BK 32

__device__ inline void gemm_tile(const u16* __restrict__ A, int lda,
                                 const u16* __restrict__ Bp, int ldb,
                                 int kBeg, int kEnd,
                                 u16* lA, u16* lB, f32x4 acc[4][4]) {
  const int tid  = threadIdx.x;
  const int lane = tid & 63, wave = tid >> 6;
  const int quad = lane >> 4, r16 = lane & 15;
  const int wm = (wave & 1) * 64, wn = (wave >> 1) * 64;

  for (int k0 = kBeg; k0 < kEnd; k0 += BK) {
    __syncthreads();  // previous iter's ds_reads done before overwrite
#pragma unroll
    for (int q = 0; q < 2; q++) {
      int s = q * 256 + tid;          // segment 0..511; within-wave: lane-contig
      int row = s >> 2, part = s & 3;
      gl_lds16(A + (size_t)row * lda + k0 + part * 8, lA + s * 8);
    }
#pragma unroll
    for (int q = 0; q < 2; q++) {
      int s = q * 256 + tid;
      int row = s >> 2, part = s & 3;
      gl_lds16(Bp + (size_t)row * ldb + k0 + part * 8, lB + s * 8);
    }
    __syncthreads();  // s_waitcnt vmcnt(0) + s_barrier (drains DMA)
    bf16x8 fa[4], fb[4];
#pragma unroll
    for (int t = 0; t < 4; t++)
      fa[t] = *(const bf16x8*)(lA + (wm + t * 16 + r16) * 32 + quad * 8);
#pragma unroll
    for (int t = 0; t < 4; t++)
      fb[t] = *(const bf16x8*)(lB + (wn + t * 16 + r16) * 32 + quad * 8);
#pragma unroll
    for (int tm = 0; tm < 4; tm++)
#pragma unroll
      for (int tn = 0; tn < 4; tn++)
        acc[tm][tn] = __builtin_amdgcn_mfma_f32_16x16x32_bf16(fa[tm], fb[tn],
                                                              acc[tm][tn], 0, 0, 0);
  }
}

// ---------------- QKV projection: [8192,1024] x [1024,1024]^T, z selects W ----------------
__global__ __launch_bounds__(256) void qkv_gemm(const u16* __restrict__ xb,
                                                const u16* __restrict__ wb,
                                                u16* __restrict__ qkv) {
  __shared__ __align__(16) u16 lA[BM * 32];
  __shared__ __align__(16) u16 lB[BN * 32];
  const int zi = blockIdx.z;
  const int row0 = blockIdx.y * BM;  // M = B*S = 8192
  const int col0 = blockIdx.x * BN;  // N = 1024
  const u16* A  = xb + (size_t)row0 * Dd;
  const u16* Bp = wb + (size_t)zi * Dd * Dd + (size_t)col0 * Dd;
  f32x4 acc[4][4];
  const f32x4 zero = {0.f, 0.f, 0.f, 0.f};
#pragma unroll
  for (int tm = 0; tm < 4; tm++)
#pragma unroll
    for (int tn = 0; tn < 4; tn++) acc[tm][tn] = zero;

  gemm_tile(A, Dd, Bp, Dd, 0, Dd, lA, lB, acc);

  u16* out = qkv + (size_t)zi * ((size_t)Bb * Ss * Dd);
  const int lane = threadIdx.x & 63, wave = threadIdx.x >> 6;
  const int quad = lane >> 4, r16 = lane & 15;
  const int wm = (wave & 1) * 64, wn = (wave >> 1) * 64;
#pragma unroll
  for (int tm = 0; tm < 4; tm++)
#pragma unroll
    for (int tn = 0; tn < 4; tn++) {
      int rr = row0 + wm + tm * 16 + quad * 4;
      int cc = col0 + wn + tn * 16 + r16;
#pragma unroll
      for (int r = 0; r < 4; r++)
        out[(size_t)(rr + r) * Dd + cc] = f2bf(acc[tm][tn][r]);
    }
}

// ---------------- scores: sc = exp(Q K^T / 32), lower tiles only, diag masked ----------------
__global__ __launch_bounds__(256) void scores_gemm(const u16* __restrict__ qb,
                                                   const u16* __restrict__ kb,
                                                   u16* __restrict__ sc) {
  const int jt = blockIdx.x, it = blockIdx.y, b = blockIdx.z;
  if (jt > it) return;  // fully-masked tile: never stored, never read downstream
  __shared__ __align__(16) u16 lA[BM * 32];
  __shared__ __align__(16) u16 lB[BN * 32];
  const u16* A  = qb + (size_t)b * Ss * Dd + (size_t)it * BM * Dd;
  const u16* Bp = kb + (size_t)b * Ss * Dd + (size_t)jt * BN * Dd;
  f32x4 acc[4][4];
  const f32x4 zero = {0.f, 0.f, 0.f, 0.f};
#pragma unroll
  for (int tm = 0; tm < 4; tm++)
#pragma unroll
    for (int tn = 0; tn < 4; tn++) acc[tm][tn] = zero;

  gemm_tile(A, Dd, Bp, Dd, 0, Dd, lA, lB, acc);

  // Unnormalized exp: scores ~N(0,1)-ish after /32, |s| << 88, so fp32 exp is
  // safe without max-subtraction. Row normalization happens in pv epilogue.
  u16* out = sc + (size_t)b * Ss * Ss;
  const int lane = threadIdx.x & 63, wave = threadIdx.x >> 6;
  const int quad = lane >> 4, r16 = lane & 15;
  const int wm = (wave & 1) * 64, wn = (wave >> 1) * 64;
#pragma unroll
  for (int tm = 0; tm < 4; tm++)
#pragma unroll
    for (int tn = 0; tn < 4; tn++) {
      int rr = it * BM + wm + tm * 16 + quad * 4;
      int cc = jt * BN + wn + tn * 16 + r16;
#pragma unroll
      for (int r = 0; r < 4; r++) {
        u16 v = (cc <= rr + r) ? f2bf(__expf(acc[tm][tn][r] * 0.03125f)) : (u16)0;
        out[(size_t)(rr + r) * Ss + cc] = v;
      }
    }
}

// ---------------- row sums -> inv_l (one wave per row) ----------------
__global__ __launch_bounds__(256) void rowsum_kernel(const u16* __restrict__ sc,
                                                     float* __restrict__ invl) {
  const int wave = threadIdx.x >> 6, lane = threadIdx.x & 63;
  const int rid = blockIdx.x * 4 + wave;  // 0..B*S-1
  const int b = rid >> 11, i = rid & 2047;
  const u16* row = sc + (size_t)b * Ss * Ss + (size_t)i * Ss;
  // diagonal tile's upper part is zero-filled, so sum through tile end
  const int n8 = ((i >> 7) + 1) * 128;
  float s = 0.f;
  for (int j = lane * 8; j < n8; j += 512) {
    bf16x8 v = *(const bf16x8*)(row + j);
#pragma unroll
    for (int t = 0; t < 8; t++) s += (float)v[t];
  }
  for (int o = 32; o; o >>= 1) s += __shfl_xor(s, o);
  if (lane == 0) invl[rid] = 1.f / s;
}

// ---------------- V transpose: vt[b,e,s] = vb[b,s,e] ----------------
__global__ __launch_bounds__(256) void transpose_v(const u16* __restrict__ vb,
                                                   u16* __restrict__ vt) {
  const int b = blockIdx.z;
  const int s0 = blockIdx.x * 64;
  const int e0 = blockIdx.y * 64;
  __shared__ __align__(16) u16 t[64][72];
  const int tid = threadIdx.x;
  const u16* src = vb + (size_t)b * Ss * Dd;
#pragma unroll
  for (int g = tid; g < 512; g += 256) {
    int row = g >> 3, part = g & 7;
    uint4 v = *(const uint4*)(src + (size_t)(s0 + row) * Dd + e0 + part * 8);
    const u16* pv = (const u16*)&v;
#pragma unroll
    for (int j = 0; j < 8; j++) t[part * 8 + j][row] = pv[j];
  }
  __syncthreads();
  u16* dst = vt + (size_t)b * Dd * Ss;
#pragma unroll
  for (int g = tid; g < 512; g += 256) {
    int e = g >> 3, part = g & 7;
    uint4 v = *(const uint4*)(&t[e][part * 8]);
    *(uint4*)(dst + (size_t)(e0 + e) * Ss + s0 + part * 8) = v;
  }
}

// ---------------- PV: O[q,e] = inv_l[q] * sum_k sc[q,k] Vt[e,k] ----------------
// 1-D grid ordered heavy-first (it descending) for load balance: K-length is
// row0+128, so it=15 blocks do 16x the work of it=0.
__global__ __launch_bounds__(256) void pv_gemm(const u16* __restrict__ sc,
                                               const u16* __restrict__ vt,
                                               const float* __restrict__ invl,
                                               float* __restrict__ out) {
  const int idx = blockIdx.x;            // 0..511
  const int it = 15 - (idx >> 5);        // heavy tiles first
  const int rem = idx & 31;
  const int col0 = (rem & 7) * BN;       // N = 1024
  const int b = rem >> 3;
  const int row0 = it * BM;
  __shared__ __align__(16) u16 lA[BM * 32];
  __shared__ __align__(16) u16 lB[BN * 32];
  const u16* A  = sc + (size_t)b * Ss * Ss + (size_t)row0 * Ss;
  const u16* Bp = vt + (size_t)b * Dd * Ss + (size_t)col0 * Ss;
  f32x4 acc[4][4];
  const f32x4 zero = {0.f, 0.f, 0.f, 0.f};
#pragma unroll
  for (int tm = 0; tm < 4; tm++)
#pragma unroll
    for (int tn = 0; tn < 4; tn++) acc[tm][tn] = zero;

  // causal: P[q,k]==0 for k > q (incl. zero-filled diag tile), K-loop clipped
  gemm_tile(A, Ss, Bp, Ss, 0, row0 + BM, lA, lB, acc);

  float* o = out + (size_t)b * Ss * Dd;
  const float* il = invl + (size_t)b * Ss;
  const int lane = threadIdx.x & 63, wave = threadIdx.x >> 6;
  const int quad = lane >> 4, r16 = lane & 15;
  const int wm = (wave & 1) * 64, wn = (wave >> 1) * 64;
#pragma unroll
  for (int tm = 0; tm < 4; tm++) {
    int rbase = row0 + wm + tm * 16 + quad * 4;
    float s0 = il[rbase], s1 = il[rbase + 1], s2 = il[rbase + 2], s3 = il[rbase + 3];
#pragma unroll
    for (int tn = 0; tn < 4; tn++) {
      int cc = col0 + wn + tn * 16 + r16;
      o[(size_t)(rbase + 0) * Dd + cc] = acc[tm][tn][0] * s0;
      o[(size_t)(rbase + 1) * Dd + cc] = acc[tm][tn][1] * s1;
      o[(size_t)(rbase + 2) * Dd + cc] = acc[tm][tn][2] * s2;
      o[(size_t)(rbase + 3) * Dd + cc] = acc[tm][tn][3] * s3;
    }
  }
}

// ---------------- launch ----------------
// Workspace layout (bytes), total 106,987,520 (~102 MB):
//   qkv : [0, 50331648)           q,k,v bf16, each 16 MB
//   sc  : [50331648, 83886080)    exp-scores bf16, 32 MB
//   xb  : [83886080, 100663296)   x bf16 16 MB; REUSED as vt after qkv_gemm
//   wb  : [100663296, 106954752)  wq|wk|wv bf16, 6 MB
//   invl: [106954752, 106987520)  per-row 1/sum fp32, 32 KB
extern "C" void kernel_launch(void* const* d_in, const int* in_sizes, int n_in,
                              void* d_out, int out_size, void* d_ws, size_t ws_size,
                              hipStream_t stream) {
  const float* x  = (const float*)d_in[0];
  const float* wq = (const float*)d_in[1];
  const float* wk = (const float*)d_in[2];
  const float* wv = (const float*)d_in[3];
  float* out = (float*)d_out;
  char* ws = (char*)d_ws;
  if (ws_size < 106987520u) return;  // clean fail rather than OOB corruption

  u16* qkv  = (u16*)(ws);
  u16* sc   = (u16*)(ws + 50331648u);
  u16* xb   = (u16*)(ws + 83886080u);
  u16* vt   = xb;  // alias: x dead after qkv_gemm
  u16* wb   = (u16*)(ws + 100663296u);
  float* invl = (float*)(ws + 106954752u);

  const size_t nQ = (size_t)Bb * Ss * Dd;  // 8388608

  cast_kernel<<<8192, 256, 0, stream>>>(x, xb, (int)nQ);
  cast3_kernel<<<dim3(1024, 3), 256, 0, stream>>>(wq, wk, wv, wb);

  qkv_gemm<<<dim3(Dd / BN, (Bb * Ss) / BM, 3), 256, 0, stream>>>(xb, wb, qkv);
  scores_gemm<<<dim3(Ss / BN, Ss / BM, Bb), 256, 0, stream>>>(qkv, qkv + nQ, sc);
  rowsum_kernel<<<(Bb * Ss) / 4, 256, 0, stream>>>(sc, invl);
  transpose_v<<<dim3(Ss / 64, Dd / 64, Bb), 256, 0, stream>>>(qkv + 2 * nQ, vt);
  pv_gemm<<<512, 256, 0, stream>>>(sc, vt, invl, out);
}

// Round 4
// 239.398 us; speedup vs baseline: 1.4034x; 1.1434x over previous
//
#include <hip/hip_runtime.h>

// Problem constants (CausalAttention: B=4, S=2048, D_IN=D_OUT=1024, single head)
#define Bb 4
#define Ss 2048
#define Dd 1024

typedef unsigned short u16;
typedef __bf16 bf16x8 __attribute__((ext_vector_type(8)));
typedef float  f32x4  __attribute__((ext_vector_type(4)));

__device__ inline u16 f2bf(float f) {
  union { float f; unsigned u; } x; x.f = f;
  unsigned u = x.u;
  return (u16)((u + 0x7fffu + ((u >> 16) & 1u)) >> 16);  // RNE
}
__device__ inline float bf2f(u16 h) {
  union { unsigned u; float f; } x; x.u = ((unsigned)h) << 16;
  return x.f;
}

// async global->LDS, 16B per lane. LDS dest is wave-uniform base + lane*16:
// lane order must match LDS contiguity.
__device__ static inline void gl_lds16(const u16* g, u16* l) {
  __builtin_amdgcn_global_load_lds((__attribute__((address_space(1))) const void*)g,
                                   (__attribute__((address_space(3))) void*)l,
                                   16, 0, 0);
}

// ---------------- cast fp32 -> bf16 (x + 3 weights in one launch) ----------------
__global__ __launch_bounds__(256) void cast_all(const float* __restrict__ x,
                                                const float* __restrict__ wq,
                                                const float* __restrict__ wk,
                                                const float* __restrict__ wv,
                                                u16* __restrict__ xb,
                                                u16* __restrict__ wb) {
  int id = blockIdx.x;
  const float* src; u16* dst; int off;
  if (id < 8192) {                      // x: 8M elements
    src = x; dst = xb; off = id * 1024;
  } else {                              // weights: 1M each
    int wi = id - 8192;
    int w = wi >> 10;
    src = (w == 0) ? wq : (w == 1) ? wk : wv;
    dst = wb + (size_t)w * Dd * Dd;
    off = (wi & 1023) * 1024;
  }
  int i = off + threadIdx.x * 4;
  float4 v = *(const float4*)(src + i);
  unsigned p0 = (unsigned)f2bf(v.x) | ((unsigned)f2bf(v.y) << 16);
  unsigned p1 = (unsigned)f2bf(v.z) | ((unsigned)f2bf(v.w) << 16);
  uint2 p; p.x = p0; p.y = p1;
  *(uint2*)(dst + i) = p;
}

// ---------------- shared GEMM core (C = A * B^T), bf16 in, fp32 acc ----------------
// LDS: unpadded, row stride 32 u16 (64B); segment s=(row*4+part) at byte s*16.
#define BM 128
#define BN 128
#define BK 32

__device__ inline void gemm_tile(const u16* __restrict__ A, int lda,
                                 const u16* __restrict__ Bp, int ldb,
                                 int kBeg, int kEnd,
                                 u16* lA, u16* lB, f32x4 acc[4][4]) {
  const int tid  = threadIdx.x;
  const int lane = tid & 63, wave = tid >> 6;
  const int quad = lane >> 4, r16 = lane & 15;
  const int wm = (wave & 1) * 64, wn = (wave >> 1) * 64;

  for (int k0 = kBeg; k0 < kEnd; k0 += BK) {
    __syncthreads();  // previous iter's ds_reads done before overwrite
#pragma unroll
    for (int q = 0; q < 2; q++) {
      int s = q * 256 + tid;          // segment 0..511; within-wave: lane-contig
      int row = s >> 2, part = s & 3;
      gl_lds16(A + (size_t)row * lda + k0 + part * 8, lA + s * 8);
    }
#pragma unroll
    for (int q = 0; q < 2; q++) {
      int s = q * 256 + tid;
      int row = s >> 2, part = s & 3;
      gl_lds16(Bp + (size_t)row * ldb + k0 + part * 8, lB + s * 8);
    }
    __syncthreads();  // s_waitcnt vmcnt(0) + s_barrier (drains DMA)
    bf16x8 fa[4], fb[4];
#pragma unroll
    for (int t = 0; t < 4; t++)
      fa[t] = *(const bf16x8*)(lA + (wm + t * 16 + r16) * 32 + quad * 8);
#pragma unroll
    for (int t = 0; t < 4; t++)
      fb[t] = *(const bf16x8*)(lB + (wn + t * 16 + r16) * 32 + quad * 8);
#pragma unroll
    for (int tm = 0; tm < 4; tm++)
#pragma unroll
      for (int tn = 0; tn < 4; tn++)
        acc[tm][tn] = __builtin_amdgcn_mfma_f32_16x16x32_bf16(fa[tm], fb[tn],
                                                              acc[tm][tn], 0, 0, 0);
  }
}

// ---------------- QKV projection, XCD-swizzled 1-D grid ----------------
// id%8 = XCD (round-robin heuristic). Each XCD gets a fixed 8-row-tile stripe
// of A (2 MB) x all B tiles (6 MB) -> per-XCD L2 working set ~6 MB vs 135 MB
// total fetch in the unswizzled version.
__global__ __launch_bounds__(256) void qkv_gemm(const u16* __restrict__ xb,
                                                const u16* __restrict__ wb,
                                                u16* __restrict__ qkv) {
  __shared__ __align__(16) u16 shmem[8192];
  u16* lA = shmem;
  u16* lB = shmem + 4096;
  const int id  = blockIdx.x;          // 0..1535
  const int xcd = id & 7, j = id >> 3; // j 0..191
  const int xt  = j & 7;               // col tile (fastest within XCD)
  const int yl  = (j >> 3) & 7;
  const int zi  = j >> 6;              // 0..2
  const int y   = xcd * 8 + yl;        // row tile 0..63
  const int row0 = y * BM;             // M = B*S = 8192
  const int col0 = xt * BN;            // N = 1024
  const u16* A  = xb + (size_t)row0 * Dd;
  const u16* Bp = wb + (size_t)zi * Dd * Dd + (size_t)col0 * Dd;
  f32x4 acc[4][4];
  const f32x4 zero = {0.f, 0.f, 0.f, 0.f};
#pragma unroll
  for (int tm = 0; tm < 4; tm++)
#pragma unroll
    for (int tn = 0; tn < 4; tn++) acc[tm][tn] = zero;

  gemm_tile(A, Dd, Bp, Dd, 0, Dd, lA, lB, acc);

  u16* out = qkv + (size_t)zi * ((size_t)Bb * Ss * Dd);
  const int lane = threadIdx.x & 63, wave = threadIdx.x >> 6;
  const int quad = lane >> 4, r16 = lane & 15;
  const int wm = (wave & 1) * 64, wn = (wave >> 1) * 64;
#pragma unroll
  for (int tm = 0; tm < 4; tm++)
#pragma unroll
    for (int tn = 0; tn < 4; tn++) {
      int rr = row0 + wm + tm * 16 + quad * 4;
      int cc = col0 + wn + tn * 16 + r16;
#pragma unroll
      for (int r = 0; r < 4; r++)
        out[(size_t)(rr + r) * Dd + cc] = f2bf(acc[tm][tn][r]);
    }
}

// ---------------- fused scores + rowsum + V-transpose ----------------
// Blocks [0,544): lower-tri score tiles -> sc = exp(QK^T/32) (diag masked),
//   with per-row partial sums atomically added into lsum (bf16-rounded p
//   summed so numerator/denominator rounding match).
// Blocks [544,1056): V transpose, 4 64x64 tiles each (work hides under scores).
__global__ __launch_bounds__(256) void scores_fused(const u16* __restrict__ qb,
                                                    const u16* __restrict__ kb,
                                                    const u16* __restrict__ vb,
                                                    u16* __restrict__ sc,
                                                    u16* __restrict__ vt,
                                                    float* __restrict__ lsum) {
  __shared__ __align__(16) u16 shmem[8192];
  const int id = blockIdx.x;
  const int tid = threadIdx.x;

  if (id >= 544) {  // ---- transpose role ----
    const int t2 = id - 544;        // 0..511
    const int b = t2 >> 7, rem = t2 & 127;
    const int e = rem >> 3, g = rem & 7;  // e-tile 0..15, s-group 0..7
    const u16* src = vb + (size_t)b * Ss * Dd;
    u16* dst = vt + (size_t)b * Dd * Ss;
    u16 (*t)[72] = (u16(*)[72])shmem;     // 64x72 u16 = 9216 <= 16384
    for (int q4 = 0; q4 < 4; q4++) {
      int s0 = (g * 4 + q4) * 64, e0 = e * 64;
      if (q4) __syncthreads();
#pragma unroll
      for (int gg = tid; gg < 512; gg += 256) {
        int row = gg >> 3, part = gg & 7;
        uint4 v = *(const uint4*)(src + (size_t)(s0 + row) * Dd + e0 + part * 8);
        const u16* pv = (const u16*)&v;
#pragma unroll
        for (int jj = 0; jj < 8; jj++) t[part * 8 + jj][row] = pv[jj];
      }
      __syncthreads();
#pragma unroll
      for (int gg = tid; gg < 512; gg += 256) {
        int ee = gg >> 3, part = gg & 7;
        uint4 v = *(const uint4*)(&t[ee][part * 8]);
        *(uint4*)(dst + (size_t)(e0 + ee) * Ss + s0 + part * 8) = v;
      }
    }
    return;
  }

  // ---- scores role ----
  // XCD swizzle: 17 consecutive tri-ids per XCD per batch (136 = 8*17).
  const int xcd = id & 7, j = id >> 3;   // j 0..67
  const int b = j / 17, tloc = j - b * 17;
  const int t = xcd * 17 + tloc;         // 0..135 lower-tri index
  int it = (int)((sqrtf(8.f * (float)t + 1.f) - 1.f) * 0.5f);
  while ((it + 1) * (it + 2) / 2 <= t) it++;
  while (it * (it + 1) / 2 > t) it--;
  const int jt = t - it * (it + 1) / 2;

  u16* lA = shmem;
  u16* lB = shmem + 4096;
  const u16* A  = qb + (size_t)b * Ss * Dd + (size_t)it * BM * Dd;
  const u16* Bp = kb + (size_t)b * Ss * Dd + (size_t)jt * BN * Dd;
  f32x4 acc[4][4];
  const f32x4 zero = {0.f, 0.f, 0.f, 0.f};
#pragma unroll
  for (int tm = 0; tm < 4; tm++)
#pragma unroll
    for (int tn = 0; tn < 4; tn++) acc[tm][tn] = zero;

  gemm_tile(A, Dd, Bp, Dd, 0, Dd, lA, lB, acc);

  // Unnormalized exp (|s/32| << 88 so fp32 exp safe without max-subtraction).
  u16* out = sc + (size_t)b * Ss * Ss;
  float* lr = lsum + (size_t)b * Ss;
  const int lane = tid & 63, wave = tid >> 6;
  const int quad = lane >> 4, r16 = lane & 15;
  const int wm = (wave & 1) * 64, wn = (wave >> 1) * 64;
#pragma unroll
  for (int tm = 0; tm < 4; tm++) {
    float psum[4] = {0.f, 0.f, 0.f, 0.f};  // per r, summed over tn
#pragma unroll
    for (int tn = 0; tn < 4; tn++) {
      int rr = it * BM + wm + tm * 16 + quad * 4;
      int cc = jt * BN + wn + tn * 16 + r16;
#pragma unroll
      for (int r = 0; r < 4; r++) {
        float p = 0.f;
        u16 h = 0;
        if (cc <= rr + r) {
          h = f2bf(__expf(acc[tm][tn][r] * 0.03125f));
          p = bf2f(h);  // sum the bf16-rounded value (matches stored numerator)
        }
        out[(size_t)(rr + r) * Ss + cc] = h;
        psum[r] += p;
      }
    }
    // reduce over the 16 lanes of this quad-row group (xor <16 stays in group)
#pragma unroll
    for (int r = 0; r < 4; r++) {
      float s = psum[r];
      s += __shfl_xor(s, 1);
      s += __shfl_xor(s, 2);
      s += __shfl_xor(s, 4);
      s += __shfl_xor(s, 8);
      if (r16 == 0) {
        int row = it * BM + wm + tm * 16 + quad * 4 + r;
        atomicAdd(&lr[row], s);
      }
    }
  }
}

// ---------------- PV: O[q,e] = (1/l[q]) * sum_k sc[q,k] Vt[e,k] ----------------
// 1-D grid ordered heavy-first (it descending): K-length is row0+128.
__global__ __launch_bounds__(256) void pv_gemm(const u16* __restrict__ sc,
                                               const u16* __restrict__ vt,
                                               const float* __restrict__ lsum,
                                               float* __restrict__ out) {
  __shared__ __align__(16) u16 shmem[8192];
  u16* lA = shmem;
  u16* lB = shmem + 4096;
  const int idx = blockIdx.x;            // 0..511
  const int it = 15 - (idx >> 5);        // heavy tiles first
  const int rem = idx & 31;
  const int col0 = (rem & 7) * BN;       // N = 1024
  const int b = rem >> 3;
  const int row0 = it * BM;
  const u16* A  = sc + (size_t)b * Ss * Ss + (size_t)row0 * Ss;
  const u16* Bp = vt + (size_t)b * Dd * Ss + (size_t)col0 * Ss;
  f32x4 acc[4][4];
  const f32x4 zero = {0.f, 0.f, 0.f, 0.f};
#pragma unroll
  for (int tm = 0; tm < 4; tm++)
#pragma unroll
    for (int tn = 0; tn < 4; tn++) acc[tm][tn] = zero;

  // causal: P[q,k]==0 for k > q (incl. zero-filled diag tile), K-loop clipped
  gemm_tile(A, Ss, Bp, Ss, 0, row0 + BM, lA, lB, acc);

  float* o = out + (size_t)b * Ss * Dd;
  const float* lr = lsum + (size_t)b * Ss;
  const int lane = threadIdx.x & 63, wave = threadIdx.x >> 6;
  const int quad = lane >> 4, r16 = lane & 15;
  const int wm = (wave & 1) * 64, wn = (wave >> 1) * 64;
#pragma unroll
  for (int tm = 0; tm < 4; tm++) {
    int rbase = row0 + wm + tm * 16 + quad * 4;
    float s0 = 1.f / lr[rbase], s1 = 1.f / lr[rbase + 1];
    float s2 = 1.f / lr[rbase + 2], s3 = 1.f / lr[rbase + 3];
#pragma unroll
    for (int tn = 0; tn < 4; tn++) {
      int cc = col0 + wn + tn * 16 + r16;
      o[(size_t)(rbase + 0) * Dd + cc] = acc[tm][tn][0] * s0;
      o[(size_t)(rbase + 1) * Dd + cc] = acc[tm][tn][1] * s1;
      o[(size_t)(rbase + 2) * Dd + cc] = acc[tm][tn][2] * s2;
      o[(size_t)(rbase + 3) * Dd + cc] = acc[tm][tn][3] * s3;
    }
  }
}

// ---------------- launch ----------------
// Workspace layout (bytes), total 106,987,520 (~102 MB):
//   qkv : [0, 50331648)           q,k,v bf16, each 16 MB
//   sc  : [50331648, 83886080)    exp-scores bf16, 32 MB
//   xb  : [83886080, 100663296)   x bf16 16 MB; REUSED as vt after qkv_gemm
//   wb  : [100663296, 106954752)  wq|wk|wv bf16, 6 MB
//   lsum: [106954752, 106987520)  per-row sum fp32, 32 KB (memset 0 each call)
extern "C" void kernel_launch(void* const* d_in, const int* in_sizes, int n_in,
                              void* d_out, int out_size, void* d_ws, size_t ws_size,
                              hipStream_t stream) {
  const float* x  = (const float*)d_in[0];
  const float* wq = (const float*)d_in[1];
  const float* wk = (const float*)d_in[2];
  const float* wv = (const float*)d_in[3];
  float* out = (float*)d_out;
  char* ws = (char*)d_ws;
  if (ws_size < 106987520u) return;  // clean fail rather than OOB corruption

  u16* qkv  = (u16*)(ws);
  u16* sc   = (u16*)(ws + 50331648u);
  u16* xb   = (u16*)(ws + 83886080u);
  u16* vt   = xb;  // alias: x dead after qkv_gemm
  u16* wb   = (u16*)(ws + 100663296u);
  float* lsum = (float*)(ws + 106954752u);

  const size_t nQ = (size_t)Bb * Ss * Dd;  // 8388608

  hipMemsetAsync(lsum, 0, Bb * Ss * sizeof(float), stream);  // graph-capturable
  cast_all<<<11264, 256, 0, stream>>>(x, wq, wk, wv, xb, wb);
  qkv_gemm<<<1536, 256, 0, stream>>>(xb, wb, qkv);
  scores_fused<<<1056, 256, 0, stream>>>(qkv, qkv + nQ, qkv + 2 * nQ, sc, vt, lsum);
  pv_gemm<<<512, 256, 0, stream>>>(sc, vt, lsum, out);
}

// Round 5
// 237.312 us; speedup vs baseline: 1.4158x; 1.0088x over previous
//
#include <hip/hip_runtime.h>

// Problem constants (CausalAttention: B=4, S=2048, D_IN=D_OUT=1024, single head)
#define Bb 4
#define Ss 2048
#define Dd 1024

typedef unsigned short u16;
typedef __bf16 bf16x8 __attribute__((ext_vector_type(8)));
typedef float  f32x4  __attribute__((ext_vector_type(4)));

__device__ inline u16 f2bf(float f) {
  union { float f; unsigned u; } x; x.f = f;
  unsigned u = x.u;
  return (u16)((u + 0x7fffu + ((u >> 16) & 1u)) >> 16);  // RNE
}
__device__ inline float bf2f(u16 h) {
  union { unsigned u; float f; } x; x.u = ((unsigned)h) << 16;
  return x.f;
}

// async global->LDS, 16B per lane. LDS dest is wave-uniform base + lane*16:
// lane order must match LDS contiguity.
__device__ static inline void gl_lds16(const u16* g, u16* l) {
  __builtin_amdgcn_global_load_lds((__attribute__((address_space(1))) const void*)g,
                                   (__attribute__((address_space(3))) void*)l,
                                   16, 0, 0);
}

// ---------------- cast fp32 -> bf16 (x + 3 weights) + lsum zeroing ----------------
// 2816 blocks x 4096 elems. Blocks 0..7 also zero lsum (runs before scores' atomics).
__global__ __launch_bounds__(256) void cast_all(const float* __restrict__ x,
                                                const float* __restrict__ wq,
                                                const float* __restrict__ wk,
                                                const float* __restrict__ wv,
                                                u16* __restrict__ xb,
                                                u16* __restrict__ wb,
                                                float* __restrict__ lsum) {
  int id = blockIdx.x;
  if (id < 8) {
    float4 z = {0.f, 0.f, 0.f, 0.f};
    ((float4*)lsum)[id * 256 + threadIdx.x] = z;
  }
  const float* src; u16* dst; int off;
  if (id < 2048) {                      // x: 8M elements
    src = x; dst = xb; off = id * 4096;
  } else {                              // weights: 1M each, 256 blocks per W
    int wi = id - 2048;
    int w = wi >> 8;
    src = (w == 0) ? wq : (w == 1) ? wk : wv;
    dst = wb + (size_t)w * Dd * Dd;
    off = (wi & 255) * 4096;
  }
#pragma unroll
  for (int t = 0; t < 4; t++) {
    int i = off + t * 1024 + threadIdx.x * 4;
    float4 v = *(const float4*)(src + i);
    unsigned p0 = (unsigned)f2bf(v.x) | ((unsigned)f2bf(v.y) << 16);
    unsigned p1 = (unsigned)f2bf(v.z) | ((unsigned)f2bf(v.w) << 16);
    uint2 p; p.x = p0; p.y = p1;
    *(uint2*)(dst + i) = p;
  }
}

// ---------------- shared GEMM core (C = A * B^T), bf16 in, fp32 acc ----------------
// BK=64 per barrier-pair via two BK=32 LDS buffer pairs (halves barrier drains
// vs the 1-buffer version; same loads, same proven 64B-row LDS layout).
// lds layout: lA0|lB0|lA1|lB1, each 4096 u16 (128 rows x 32, unpadded).
#define BM 128
#define BN 128

__device__ inline void gemm_tile(const u16* __restrict__ A, int lda,
                                 const u16* __restrict__ Bp, int ldb,
                                 int kBeg, int kEnd,  // multiples of 64
                                 u16* lds, f32x4 acc[4][4]) {
  u16* lA0 = lds;
  u16* lB0 = lds + 4096;
  u16* lA1 = lds + 8192;
  u16* lB1 = lds + 12288;
  const int tid  = threadIdx.x;
  const int lane = tid & 63, wave = tid >> 6;
  const int quad = lane >> 4, r16 = lane & 15;
  const int wm = (wave & 1) * 64, wn = (wave >> 1) * 64;
  const int r0 = tid >> 2, part = tid & 3;  // seg s=q*256+tid -> row=q*64+r0

  for (int k0 = kBeg; k0 < kEnd; k0 += 64) {
    __syncthreads();  // previous halves' ds_reads done before overwrite
#pragma unroll
    for (int q = 0; q < 2; q++) {
      int row = q * 64 + r0;
      int s8 = (q * 256 + tid) * 8;
      const u16* ga = A  + (size_t)row * lda + k0 + part * 8;
      const u16* gb = Bp + (size_t)row * ldb + k0 + part * 8;
      gl_lds16(ga,      lA0 + s8);
      gl_lds16(gb,      lB0 + s8);
      gl_lds16(ga + 32, lA1 + s8);
      gl_lds16(gb + 32, lB1 + s8);
    }
    __syncthreads();  // one vmcnt(0) drain per 64-K (was per 32-K)
#pragma unroll
    for (int h = 0; h < 2; h++) {
      const u16* la = h ? lA1 : lA0;
      const u16* lb = h ? lB1 : lB0;
      bf16x8 fa[4], fb[4];
#pragma unroll
      for (int t = 0; t < 4; t++)
        fa[t] = *(const bf16x8*)(la + (wm + t * 16 + r16) * 32 + quad * 8);
#pragma unroll
      for (int t = 0; t < 4; t++)
        fb[t] = *(const bf16x8*)(lb + (wn + t * 16 + r16) * 32 + quad * 8);
#pragma unroll
      for (int tm = 0; tm < 4; tm++)
#pragma unroll
        for (int tn = 0; tn < 4; tn++)
          acc[tm][tn] = __builtin_amdgcn_mfma_f32_16x16x32_bf16(fa[tm], fb[tn],
                                                                acc[tm][tn], 0, 0, 0);
    }
  }
}

// ---------------- QKV projection, XCD-swizzled 1-D grid ----------------
// id%8 = XCD. Each XCD gets a fixed 8-row-tile stripe of A x all B tiles
// -> per-XCD L2 working set ~6 MB (FETCH 135->49 MB measured r4).
__global__ __launch_bounds__(256) void qkv_gemm(const u16* __restrict__ xb,
                                                const u16* __restrict__ wb,
                                                u16* __restrict__ qkv) {
  __shared__ __align__(16) u16 shmem[16384];
  const int id  = blockIdx.x;          // 0..1535
  const int xcd = id & 7, j = id >> 3; // j 0..191
  const int xt  = j & 7;               // col tile (fastest within XCD)
  const int yl  = (j >> 3) & 7;
  const int zi  = j >> 6;              // 0..2
  const int y   = xcd * 8 + yl;        // row tile 0..63
  const int row0 = y * BM;             // M = B*S = 8192
  const int col0 = xt * BN;            // N = 1024
  const u16* A  = xb + (size_t)row0 * Dd;
  const u16* Bp = wb + (size_t)zi * Dd * Dd + (size_t)col0 * Dd;
  f32x4 acc[4][4];
  const f32x4 zero = {0.f, 0.f, 0.f, 0.f};
#pragma unroll
  for (int tm = 0; tm < 4; tm++)
#pragma unroll
    for (int tn = 0; tn < 4; tn++) acc[tm][tn] = zero;

  gemm_tile(A, Dd, Bp, Dd, 0, Dd, shmem, acc);

  u16* out = qkv + (size_t)zi * ((size_t)Bb * Ss * Dd);
  const int lane = threadIdx.x & 63, wave = threadIdx.x >> 6;
  const int quad = lane >> 4, r16 = lane & 15;
  const int wm = (wave & 1) * 64, wn = (wave >> 1) * 64;
#pragma unroll
  for (int tm = 0; tm < 4; tm++)
#pragma unroll
    for (int tn = 0; tn < 4; tn++) {
      int rr = row0 + wm + tm * 16 + quad * 4;
      int cc = col0 + wn + tn * 16 + r16;
#pragma unroll
      for (int r = 0; r < 4; r++)
        out[(size_t)(rr + r) * Dd + cc] = f2bf(acc[tm][tn][r]);
    }
}

// ---------------- fused scores + rowsum + V-transpose ----------------
// Blocks [0,544): lower-tri score tiles -> sc = exp(QK^T/32) (diag masked),
//   per-row partial sums atomically added into lsum (bf16-rounded p summed so
//   numerator/denominator rounding match).
// Blocks [544,1024): V transpose, grid-stride over 2048 64x64 tiles.
__global__ __launch_bounds__(256) void scores_fused(const u16* __restrict__ qb,
                                                    const u16* __restrict__ kb,
                                                    const u16* __restrict__ vb,
                                                    u16* __restrict__ sc,
                                                    u16* __restrict__ vt,
                                                    float* __restrict__ lsum) {
  __shared__ __align__(16) u16 shmem[16384];
  const int id = blockIdx.x;
  const int tid = threadIdx.x;

  if (id >= 544) {  // ---- transpose role ----
    const int bid = id - 544;            // 0..479
    u16 (*t)[72] = (u16(*)[72])shmem;    // 64x72 u16 = 9216 <= 16384
    for (int u = bid; u < 2048; u += 480) {
      const int b = u >> 9, rem = u & 511;
      const int e0 = (rem >> 5) * 64, s0 = (rem & 31) * 64;
      const u16* src = vb + (size_t)b * Ss * Dd;
      u16* dst = vt + (size_t)b * Dd * Ss;
      if (u != bid) __syncthreads();
#pragma unroll
      for (int gg = tid; gg < 512; gg += 256) {
        int row = gg >> 3, prt = gg & 7;
        uint4 v = *(const uint4*)(src + (size_t)(s0 + row) * Dd + e0 + prt * 8);
        const u16* pv = (const u16*)&v;
#pragma unroll
        for (int jj = 0; jj < 8; jj++) t[prt * 8 + jj][row] = pv[jj];
      }
      __syncthreads();
#pragma unroll
      for (int gg = tid; gg < 512; gg += 256) {
        int ee = gg >> 3, prt = gg & 7;
        uint4 v = *(const uint4*)(&t[ee][prt * 8]);
        *(uint4*)(dst + (size_t)(e0 + ee) * Ss + s0 + prt * 8) = v;
      }
    }
    return;
  }

  // ---- scores role ----
  // XCD swizzle: 17 consecutive tri-ids per XCD per batch (136 = 8*17).
  const int xcd = id & 7, j = id >> 3;   // j 0..67
  const int b = j / 17, tloc = j - b * 17;
  const int t = xcd * 17 + tloc;         // 0..135 lower-tri index
  int it = (int)((sqrtf(8.f * (float)t + 1.f) - 1.f) * 0.5f);
  while ((it + 1) * (it + 2) / 2 <= t) it++;
  while (it * (it + 1) / 2 > t) it--;
  const int jt = t - it * (it + 1) / 2;

  const u16* A  = qb + (size_t)b * Ss * Dd + (size_t)it * BM * Dd;
  const u16* Bp = kb + (size_t)b * Ss * Dd + (size_t)jt * BN * Dd;
  f32x4 acc[4][4];
  const f32x4 zero = {0.f, 0.f, 0.f, 0.f};
#pragma unroll
  for (int tm = 0; tm < 4; tm++)
#pragma unroll
    for (int tn = 0; tn < 4; tn++) acc[tm][tn] = zero;

  gemm_tile(A, Dd, Bp, Dd, 0, Dd, shmem, acc);

  // Unnormalized exp (|s/32| << 88 so fp32 exp safe without max-subtraction).
  u16* out = sc + (size_t)b * Ss * Ss;
  float* lr = lsum + (size_t)b * Ss;
  const int lane = tid & 63, wave = tid >> 6;
  const int quad = lane >> 4, r16 = lane & 15;
  const int wm = (wave & 1) * 64, wn = (wave >> 1) * 64;
#pragma unroll
  for (int tm = 0; tm < 4; tm++) {
    float psum[4] = {0.f, 0.f, 0.f, 0.f};  // per r, summed over tn
#pragma unroll
    for (int tn = 0; tn < 4; tn++) {
      int rr = it * BM + wm + tm * 16 + quad * 4;
      int cc = jt * BN + wn + tn * 16 + r16;
#pragma unroll
      for (int r = 0; r < 4; r++) {
        float p = 0.f;
        u16 h = 0;
        if (cc <= rr + r) {
          h = f2bf(__expf(acc[tm][tn][r] * 0.03125f));
          p = bf2f(h);  // sum the bf16-rounded value (matches stored numerator)
        }
        out[(size_t)(rr + r) * Ss + cc] = h;
        psum[r] += p;
      }
    }
#pragma unroll
    for (int r = 0; r < 4; r++) {
      float s = psum[r];
      s += __shfl_xor(s, 1);
      s += __shfl_xor(s, 2);
      s += __shfl_xor(s, 4);
      s += __shfl_xor(s, 8);
      if (r16 == 0) {
        int row = it * BM + wm + tm * 16 + quad * 4 + r;
        atomicAdd(&lr[row], s);
      }
    }
  }
}

// ---------------- PV: O[q,e] = (1/l[q]) * sum_k sc[q,k] Vt[e,k] ----------------
// it-slot order {15,13,11,9,7,5,3,1,0,2,4,6,8,10,12,14}: with 2 blocks/CU
// resident, block c pairs with c+256 and slot pairs (s, s+8) sum to it=15
// -> uniform 68 K-iters per CU (the old heavy-first order paired 96-vs-40).
__global__ __launch_bounds__(256) void pv_gemm(const u16* __restrict__ sc,
                                               const u16* __restrict__ vt,
                                               const float* __restrict__ lsum,
                                               float* __restrict__ out) {
  __shared__ __align__(16) u16 shmem[16384];
  const int idx = blockIdx.x;            // 0..511
  const int slot = idx >> 5;
  const int it = (slot < 8) ? (15 - 2 * slot) : (2 * (slot - 8));
  const int rem = idx & 31;
  const int col0 = (rem & 7) * BN;       // N = 1024
  const int b = rem >> 3;
  const int row0 = it * BM;
  const u16* A  = sc + (size_t)b * Ss * Ss + (size_t)row0 * Ss;
  const u16* Bp = vt + (size_t)b * Dd * Ss + (size_t)col0 * Ss;
  f32x4 acc[4][4];
  const f32x4 zero = {0.f, 0.f, 0.f, 0.f};
#pragma unroll
  for (int tm = 0; tm < 4; tm++)
#pragma unroll
    for (int tn = 0; tn < 4; tn++) acc[tm][tn] = zero;

  // causal: P[q,k]==0 for k > q (incl. zero-filled diag tile), K-loop clipped
  gemm_tile(A, Ss, Bp, Ss, 0, row0 + BM, shmem, acc);

  float* o = out + (size_t)b * Ss * Dd;
  const float* lr = lsum + (size_t)b * Ss;
  const int lane = threadIdx.x & 63, wave = threadIdx.x >> 6;
  const int quad = lane >> 4, r16 = lane & 15;
  const int wm = (wave & 1) * 64, wn = (wave >> 1) * 64;
#pragma unroll
  for (int tm = 0; tm < 4; tm++) {
    int rbase = row0 + wm + tm * 16 + quad * 4;
    float s0 = 1.f / lr[rbase], s1 = 1.f / lr[rbase + 1];
    float s2 = 1.f / lr[rbase + 2], s3 = 1.f / lr[rbase + 3];
#pragma unroll
    for (int tn = 0; tn < 4; tn++) {
      int cc = col0 + wn + tn * 16 + r16;
      o[(size_t)(rbase + 0) * Dd + cc] = acc[tm][tn][0] * s0;
      o[(size_t)(rbase + 1) * Dd + cc] = acc[tm][tn][1] * s1;
      o[(size_t)(rbase + 2) * Dd + cc] = acc[tm][tn][2] * s2;
      o[(size_t)(rbase + 3) * Dd + cc] = acc[tm][tn][3] * s3;
    }
  }
}

// ---------------- launch ----------------
// Workspace layout (bytes), total 106,987,520 (~102 MB):
//   qkv : [0, 50331648)           q,k,v bf16, each 16 MB
//   sc  : [50331648, 83886080)    exp-scores bf16, 32 MB
//   xb  : [83886080, 100663296)   x bf16 16 MB; REUSED as vt after qkv_gemm
//   wb  : [100663296, 106954752)  wq|wk|wv bf16, 6 MB
//   lsum: [106954752, 106987520)  per-row sum fp32, 32 KB (zeroed by cast_all)
extern "C" void kernel_launch(void* const* d_in, const int* in_sizes, int n_in,
                              void* d_out, int out_size, void* d_ws, size_t ws_size,
                              hipStream_t stream) {
  const float* x  = (const float*)d_in[0];
  const float* wq = (const float*)d_in[1];
  const float* wk = (const float*)d_in[2];
  const float* wv = (const float*)d_in[3];
  float* out = (float*)d_out;
  char* ws = (char*)d_ws;
  if (ws_size < 106987520u) return;  // clean fail rather than OOB corruption

  u16* qkv  = (u16*)(ws);
  u16* sc   = (u16*)(ws + 50331648u);
  u16* xb   = (u16*)(ws + 83886080u);
  u16* vt   = xb;  // alias: x dead after qkv_gemm
  u16* wb   = (u16*)(ws + 100663296u);
  float* lsum = (float*)(ws + 106954752u);

  const size_t nQ = (size_t)Bb * Ss * Dd;  // 8388608

  cast_all<<<2816, 256, 0, stream>>>(x, wq, wk, wv, xb, wb, lsum);
  qkv_gemm<<<1536, 256, 0, stream>>>(xb, wb, qkv);
  scores_fused<<<1024, 256, 0, stream>>>(qkv, qkv + nQ, qkv + 2 * nQ, sc, vt, lsum);
  pv_gemm<<<512, 256, 0, stream>>>(sc, vt, lsum, out);
}